// Round 21
// baseline (199.455 us; speedup 1.0000x reference)
//
#include <hip/hip_runtime.h>

#define FEAT 14
#define ROLE_DIM 16
#define IDX_DIM 8
#define IN_DIM 38       // 14 + 16 + 8
#define HID 128
#define IDX_VOCAB 1024
#define BINN 64         // nodes per bin (64 -> 25.6KB LDS agg kernel, 6 blk/CU)
#define NBINS_MAX 1600  // static LDS sizing (1563 actual)
#define NSEG 512        // binning blocks (= segments per bin); lambda~2.5
#define BINP_CAPT 6     // LDS buffer entries per bin per binp block
#define BINP_SCAP 16    // staged capacity per (bin, seg) = one 64B line
#define SORT_CAP 2048   // per-bin total entries ~1280 avg (21 sigma headroom)
#define SENT 0xFFFFFFFFu  // terminator (legit entries have bit25==0)

typedef __attribute__((ext_vector_type(8))) short short8;
typedef __attribute__((ext_vector_type(4))) float f32x4;
typedef __attribute__((ext_vector_type(2))) float f32x2;

// bf16 round-to-nearest-even pack
__device__ __forceinline__ ushort f2bf(float f) {
    uint u = __float_as_uint(f);
    return (ushort)((u + 0x7FFFu + ((u >> 16) & 1u)) >> 16);
}
__device__ __forceinline__ float bf2f(ushort h) {
    return __uint_as_float((uint)h << 16);
}
// fp8 e4m3 (OCP on gfx950) encode
__device__ __forceinline__ uchar f2fp8(float f) {
    return (uchar)(__builtin_amdgcn_cvt_pk_fp8_f32(f, f, 0, false) & 0xff);
}

// ---------------------------------------------------------------------------
// Prep: bf16 + transpose of the 4 weight matrices.
// ---------------------------------------------------------------------------
__global__ void k_prep(const float* __restrict__ W1, const float* __restrict__ W2,
                       const float* __restrict__ M1, const float* __restrict__ M2,
                       ushort* __restrict__ W1t, ushort* __restrict__ W2t,
                       ushort* __restrict__ M1t, ushort* __restrict__ M2t)
{
    int t = blockIdx.x * 256 + threadIdx.x;
    if (t < 8192) {                    // W1t: 128 x 64
        int c = t >> 6, k = t & 63;
        W1t[t] = (k < IN_DIM) ? f2bf(W1[k * HID + c]) : (ushort)0;
    } else if (t < 24576) {            // W2t: 128 x 128
        int u = t - 8192; int c = u >> 7, k = u & 127;
        W2t[u] = f2bf(W2[k * HID + c]);
    } else if (t < 40960) {            // M1t
        int u = t - 24576; int c = u >> 7, k = u & 127;
        M1t[u] = f2bf(M1[k * HID + c]);
    } else if (t < 57344) {            // M2t
        int u = t - 40960; int c = u >> 7, k = u & 127;
        M2t[u] = f2bf(M2[k * HID + c]);
    }
}

// ---------------------------------------------------------------------------
// Embed role: embh = bf16(relu(relu(x@W1+b1)@W2+b2)); embf8 = fp8 replica.
// ---------------------------------------------------------------------------
#define LDSA 32768

__device__ __forceinline__ void embed_body(
    char* lds, int id,
    const float* __restrict__ feat, const int* __restrict__ role_ids,
    const float* __restrict__ role_emb, const float* __restrict__ idx_emb,
    const ushort* __restrict__ W1t, const float* __restrict__ b1,
    const ushort* __restrict__ W2t, const float* __restrict__ b2,
    ushort* __restrict__ embh, uchar* __restrict__ embf8, int N)
{
    const int tid = threadIdx.x;
    const int w = tid >> 6, l = tid & 63;
    const int li = l & 15, hi = l >> 4;
    const int base = id * 64;

    // stage W1t (16KB) : [128 cols][64 k] -> 8 x 16B chunks per col
    for (int c = 0; c < 4; ++c) {
        int idx = c * 256 + tid;
        int col = idx >> 3, ch = idx & 7;
        uint4 v = *(const uint4*)(W1t + col * 64 + ch * 8);
        *(uint4*)(lds + col * 256 + ((ch * 16) ^ ((col & 7) << 4))) = v;
    }
    // build x-tile [64 rows][64 k] bf16 at LDSA
    {
        int row = tid >> 2, kq = (tid & 3) * 16;
        int gr = base + row; if (gr >= N) gr = N - 1;
        int rid = role_ids[gr];
        float xv[16];
        #pragma unroll
        for (int j = 0; j < 16; ++j) {
            int k = kq + j;
            float v = 0.0f;
            if (k < FEAT)                 v = feat[gr * FEAT + k];
            else if (k < FEAT + ROLE_DIM) v = role_emb[rid * ROLE_DIM + (k - FEAT)];
            else if (k < IN_DIM)          v = idx_emb[(gr & (IDX_VOCAB - 1)) * IDX_DIM + (k - FEAT - ROLE_DIM)];
            xv[j] = v;
        }
        uint p[8];
        #pragma unroll
        for (int j = 0; j < 8; ++j)
            p[j] = (uint)f2bf(xv[2 * j]) | ((uint)f2bf(xv[2 * j + 1]) << 16);
        char* db = lds + LDSA + row * 256;
        int sw = (row & 7) << 4;
        *(uint4*)(db + ((kq * 2) ^ sw))      = make_uint4(p[0], p[1], p[2], p[3]);
        *(uint4*)(db + ((kq * 2 + 16) ^ sw)) = make_uint4(p[4], p[5], p[6], p[7]);
    }
    __syncthreads();

    // phase 1: K=64
    f32x4 C[8];
    #pragma unroll
    for (int ct = 0; ct < 8; ++ct) C[ct] = (f32x4){0.f, 0.f, 0.f, 0.f};
    {
        const int arow = w * 16 + li;
        const int asw = (arow & 7) << 4;
        #pragma unroll
        for (int ks = 0; ks < 2; ++ks) {
            short8 a = *(short8*)(lds + LDSA + arow * 256 + ((ks * 64 + hi * 16) ^ asw));
            #pragma unroll
            for (int ct = 0; ct < 8; ++ct) {
                int bcol = ct * 16 + li;
                short8 b = *(short8*)(lds + bcol * 256 + ((ks * 64 + hi * 16) ^ ((bcol & 7) << 4)));
                C[ct] = __builtin_amdgcn_mfma_f32_16x16x32_bf16(a, b, C[ct], 0, 0, 0);
            }
        }
    }
    __syncthreads();

    // H = relu(C+b1) bf16 -> LDSA; stage W2t (32KB)
    #pragma unroll
    for (int ct = 0; ct < 8; ++ct) {
        int col = ct * 16 + li;
        float bv = b1[col];
        #pragma unroll
        for (int r = 0; r < 4; ++r) {
            int hrow = w * 16 + hi * 4 + r;
            float h = fmaxf(C[ct][r] + bv, 0.0f);
            *(ushort*)(lds + LDSA + hrow * 256 + ((col * 2) ^ ((hrow & 7) << 4))) = f2bf(h);
        }
    }
    for (int c = 0; c < 8; ++c) {
        int idx = c * 256 + tid;
        int col = idx >> 4, ch = idx & 15;
        uint4 v = *(const uint4*)(W2t + col * 128 + ch * 8);
        *(uint4*)(lds + col * 256 + ((ch * 16) ^ ((col & 7) << 4))) = v;
    }
    __syncthreads();

    // phase 2: K=128
    f32x4 C2[8];
    #pragma unroll
    for (int ct = 0; ct < 8; ++ct) C2[ct] = (f32x4){0.f, 0.f, 0.f, 0.f};
    {
        const int arow = w * 16 + li;
        const int asw = (arow & 7) << 4;
        #pragma unroll
        for (int ks = 0; ks < 4; ++ks) {
            short8 a = *(short8*)(lds + LDSA + arow * 256 + ((ks * 64 + hi * 16) ^ asw));
            #pragma unroll
            for (int ct = 0; ct < 8; ++ct) {
                int bcol = ct * 16 + li;
                short8 b = *(short8*)(lds + bcol * 256 + ((ks * 64 + hi * 16) ^ ((bcol & 7) << 4)));
                C2[ct] = __builtin_amdgcn_mfma_f32_16x16x32_bf16(a, b, C2[ct], 0, 0, 0);
            }
        }
    }

    // epilogue
    #pragma unroll
    for (int ct = 0; ct < 8; ++ct) {
        int col = ct * 16 + li;
        float bv = b2[col];
        #pragma unroll
        for (int r = 0; r < 4; ++r) {
            int gr = base + w * 16 + hi * 4 + r;
            if (gr < N) {
                float o = fmaxf(C2[ct][r] + bv, 0.0f);
                embh[(size_t)gr * 128 + col] = f2bf(o);
                embf8[(size_t)gr * 128 + col] = f2fp8(o);
            }
        }
    }
}

// ---------------------------------------------------------------------------
// Binp role: LDS-buffered private-segment binning + fused pin histogram.
// 64-node bins (bin = node>>6, 1563 bins). Self-describing segments (SENT).
// entry (4B) = (node&63)<<26 | nbr<<8 | round(w*255)  (bit25 always 0).
// ---------------------------------------------------------------------------
__device__ __forceinline__ void binp_body(
    char* lds, int id,
    const int* __restrict__ src, const int* __restrict__ dst,
    const float* __restrict__ wgt, uint* __restrict__ staged,
    const int* __restrict__ pb, const float* __restrict__ pv,
    float* __restrict__ pw,
    int E, int P, int nbins, int chunkE, int chunkP)
{
    uint* buf   = (uint*)lds;                        // 1600*6*4 = 38400
    int* curT   = (int*)(lds + 38400);               // 6400
    const int tid = threadIdx.x;
    for (int i = tid; i < nbins; i += 256) curT[i] = 0;
    __syncthreads();

    const int lo = id * chunkE;
    const int hiE = (lo + chunkE) < E ? (lo + chunkE) : E;
    for (int i = lo + tid; i < hiE; i += 256) {
        int s = src[i], d = dst[i];
        uint q = (uint)(wgt[i] * 255.0f + 0.5f);
        int bs = s >> 6;
        uint es = ((uint)(s & 63) << 26) | ((uint)d << 8) | q;
        int ps = atomicAdd(&curT[bs], 1);
        if (ps < BINP_CAPT) buf[bs * BINP_CAPT + ps] = es;
        else if (ps < BINP_SCAP)
            staged[((size_t)bs * NSEG + id) * BINP_SCAP + ps] = es;
        int bd = d >> 6;
        uint ed = ((uint)(d & 63) << 26) | ((uint)s << 8) | q;
        int pd = atomicAdd(&curT[bd], 1);
        if (pd < BINP_CAPT) buf[bd * BINP_CAPT + pd] = ed;
        else if (pd < BINP_SCAP)
            staged[((size_t)bd * NSEG + id) * BINP_SCAP + pd] = ed;
    }
    __syncthreads();
    for (int b = tid; b < nbins; b += 256) {
        int tot = curT[b];
        int k = tot < BINP_CAPT ? tot : BINP_CAPT;
        uint* dp = staged + ((size_t)b * NSEG + id) * BINP_SCAP;
        for (int i = 0; i < k; ++i) dp[i] = buf[b * BINP_CAPT + i];
        if (tot < BINP_SCAP) dp[tot] = SENT;   // terminator (same 64B line)
    }

    // fused pin-weight histogram (1M atomics over 100K addresses — fine)
    int loP = id * chunkP;
    int hiP = loP + chunkP; if (hiP > P) hiP = P;
    for (int i = loP + tid; i < hiP; i += 256)
        atomicAdd(&pw[pb[i]], pv[i]);
}

// ---------------------------------------------------------------------------
// Merged heterogeneous dispatch: interleaved embed / binp blocks.
// ---------------------------------------------------------------------------
__global__ __launch_bounds__(256) void k_embed_binp(
    const float* __restrict__ feat, const int* __restrict__ role_ids,
    const float* __restrict__ role_emb, const float* __restrict__ idx_emb,
    const ushort* __restrict__ W1t, const float* __restrict__ b1,
    const ushort* __restrict__ W2t, const float* __restrict__ b2,
    ushort* __restrict__ embh, uchar* __restrict__ embf8,
    const int* __restrict__ src, const int* __restrict__ dst,
    const float* __restrict__ wgt, uint* __restrict__ staged,
    const int* __restrict__ pb, const float* __restrict__ pv,
    float* __restrict__ pw,
    int N, int E, int P, int nbins, int chunkE, int chunkP)
{
    __shared__ char lds[49152];
    const int bid = blockIdx.x;
    int role, id;
    if (bid < 2 * NSEG) { role = bid & 1; id = bid >> 1; }
    else                { role = 0; id = NSEG + (bid - 2 * NSEG); }

    if (role == 0)
        embed_body(lds, id, feat, role_ids, role_emb, idx_emb,
                   W1t, b1, W2t, b2, embh, embf8, N);
    else
        binp_body(lds, id, src, dst, wgt, staged, pb, pv, pw,
                  E, P, nbins, chunkE, chunkP);
}

// ---------------------------------------------------------------------------
// FUSED k_agg_mlp v3: 64-node bins, 25.6KB LDS -> 6 blocks/CU (was 51.2KB
// -> 3; kernel is latency-bound at ~20% on every pipe, occupancy is the
// lever). Weights staged in 8KB K-quarters into the dead sort region
// (linear layout: 16 lanes/col x 64B stride = 2-way bank alias = free).
// LDS: [0,8K) sorted / weight-quarters / wsum; [8K,9K) aux;
//      [9K,25.6K) A-tile 64 rows x 256B.
// ---------------------------------------------------------------------------
#define AOFF  9216
#define AUXO  8192

__global__ __launch_bounds__(256) void k_agg_mlp(
    const uint* __restrict__ staged,
    const ushort* __restrict__ embh, const uchar* __restrict__ embf8,
    const float* __restrict__ pw,
    const ushort* __restrict__ M1t, const ushort* __restrict__ M2t,
    const float* __restrict__ mb1, const float* __restrict__ mb2,
    const float* __restrict__ ln_g, const float* __restrict__ ln_b,
    float* __restrict__ out, float* __restrict__ gsum, int N, int nbins)
{
    __shared__ char lds[25600];
    uint* sorted  = (uint*)lds;                    // [0,8K)
    int*  hist    = (int*)(lds + AUXO);            // 256B each
    int*  startL  = (int*)(lds + AUXO + 256);
    int*  curL    = (int*)(lds + AUXO + 512);
    int*  sc      = (int*)(lds + AUXO + 768);

    const int tid = threadIdx.x;
    const int b = blockIdx.x;
    const int baseNode = b << 6;
    const int w = tid >> 6, l = tid & 63;
    const int li = l & 15, hi = l >> 4;

    if (tid < BINN) hist[tid] = 0;
    __syncthreads();

    // ---- Phase A: load 2 segments (4x uint4 each) into registers ----
    uint4 ent[2][4];
    int cSeg[2];
    #pragma unroll
    for (int ss = 0; ss < 2; ++ss) {
        int seg = ss * 256 + tid;
        const uint4* sp4 = (const uint4*)(staged + ((size_t)b * NSEG + seg) * BINP_SCAP);
        #pragma unroll
        for (int q = 0; q < 4; ++q) ent[ss][q] = sp4[q];
        int c = 16;
        #pragma unroll
        for (int q = 3; q >= 0; --q) {
            if (ent[ss][q].w == SENT) c = q * 4 + 3;
            if (ent[ss][q].z == SENT) c = q * 4 + 2;
            if (ent[ss][q].y == SENT) c = q * 4 + 1;
            if (ent[ss][q].x == SENT) c = q * 4 + 0;
        }
        cSeg[ss] = c;
    }
    // histogram from registers (node = e>>26)
    #pragma unroll
    for (int ss = 0; ss < 2; ++ss) {
        int c = cSeg[ss];
        #pragma unroll
        for (int q = 0; q < 4; ++q) {
            uint e0 = ent[ss][q].x, e1 = ent[ss][q].y;
            uint e2 = ent[ss][q].z, e3 = ent[ss][q].w;
            if (q * 4 + 0 < c) atomicAdd(&hist[e0 >> 26], 1);
            if (q * 4 + 1 < c) atomicAdd(&hist[e1 >> 26], 1);
            if (q * 4 + 2 < c) atomicAdd(&hist[e2 >> 26], 1);
            if (q * 4 + 3 < c) atomicAdd(&hist[e3 >> 26], 1);
        }
    }
    __syncthreads();

    int v = (tid < BINN) ? hist[tid] : 0;
    if (tid < BINN) sc[tid] = v;
    __syncthreads();
    for (int off = 1; off < BINN; off <<= 1) {
        int u = (tid < BINN && tid >= off) ? sc[tid - off] : 0;
        __syncthreads();
        if (tid < BINN) sc[tid] += u;
        __syncthreads();
    }
    if (tid < BINN) {
        startL[tid] = sc[tid] - v;
        curL[tid]   = sc[tid] - v;
    }
    __syncthreads();

    // placement from registers
    #pragma unroll
    for (int ss = 0; ss < 2; ++ss) {
        int c = cSeg[ss];
        #pragma unroll
        for (int q = 0; q < 4; ++q) {
            uint ee[4] = {ent[ss][q].x, ent[ss][q].y, ent[ss][q].z, ent[ss][q].w};
            #pragma unroll
            for (int j = 0; j < 4; ++j) {
                if (q * 4 + j < c) {
                    uint e = ee[j];
                    int pos = atomicAdd(&curL[e >> 26], 1);
                    if (pos < SORT_CAP) sorted[pos] = e;
                }
            }
        }
    }
    __syncthreads();

    // ---- Phase B: gather -> bf16 A-tile in LDS (2 rounds x 32 nodes) ----
    {
        const int g  = tid >> 3;
        const int cg = tid & 7;
        const int c0 = cg * 16;
        for (int h = 0; h < 2; ++h) {
            int nl = h * 32 + g;
            int node = baseNode + nl;
            uint p[8];
            if (node < N) {
                float acc[16];
                float pwn = pw[node];
                const uint4* r = (const uint4*)(embh + ((size_t)node << 7) + c0);
                uint4 u0 = r[0], u1 = r[1];
                uint uu[8] = {u0.x, u0.y, u0.z, u0.w, u1.x, u1.y, u1.z, u1.w};
                #pragma unroll
                for (int j = 0; j < 8; ++j) {
                    acc[2*j]   = __uint_as_float(uu[j] << 16) * pwn;
                    acc[2*j+1] = __uint_as_float(uu[j] & 0xffff0000u) * pwn;
                }
                const int st = startL[nl], deg = hist[nl];
                #pragma unroll 4
                for (int i = 0; i < deg; ++i) {
                    uint en = sorted[st + i];
                    int nb   = (int)((en >> 8) & 0x1FFFFu);
                    float wt = (float)(en & 255u) * (1.0f / 255.0f);
                    uint4 q = *(const uint4*)(embf8 + ((size_t)nb << 7) + c0);
                    uint qq[4] = {q.x, q.y, q.z, q.w};
                    #pragma unroll
                    for (int j = 0; j < 4; ++j) {
                        f32x2 lo = __builtin_amdgcn_cvt_pk_f32_fp8(qq[j], false);
                        f32x2 hi2 = __builtin_amdgcn_cvt_pk_f32_fp8(qq[j], true);
                        acc[4*j+0] = fmaf(lo.x,  wt, acc[4*j+0]);
                        acc[4*j+1] = fmaf(lo.y,  wt, acc[4*j+1]);
                        acc[4*j+2] = fmaf(hi2.x, wt, acc[4*j+2]);
                        acc[4*j+3] = fmaf(hi2.y, wt, acc[4*j+3]);
                    }
                }
                #pragma unroll
                for (int j = 0; j < 8; ++j)
                    p[j] = (uint)f2bf(acc[2*j]) | ((uint)f2bf(acc[2*j+1]) << 16);
            } else {
                #pragma unroll
                for (int j = 0; j < 8; ++j) p[j] = 0;
            }
            char* db = lds + AOFF + nl * 256;
            int sw = (nl & 7) << 4;
            *(uint4*)(db + ((c0 * 2) ^ sw))      = make_uint4(p[0], p[1], p[2], p[3]);
            *(uint4*)(db + ((c0 * 2 + 16) ^ sw)) = make_uint4(p[4], p[5], p[6], p[7]);
        }
    }

    const int arow = w * 16 + li;           // 0..63 (whole bin in one pass)
    const int asw  = (arow & 7) << 4;

    // ---- Phase D: MLP1, weights staged in 8KB K-quarters (linear) ----
    f32x4 C1[8];
    #pragma unroll
    for (int ct = 0; ct < 8; ++ct) C1[ct] = (f32x4){0.f, 0.f, 0.f, 0.f};
    #pragma unroll
    for (int kq = 0; kq < 4; ++kq) {
        __syncthreads();   // sorted region reads done / prior quarter done
        for (int cc = 0; cc < 2; ++cc) {
            int idx = cc * 256 + tid;       // 0..511 (16B chunks)
            int col = idx >> 2, ch = idx & 3;
            uint4 vv = *(const uint4*)(M1t + col * 128 + kq * 32 + ch * 8);
            *(uint4*)(lds + col * 64 + ch * 16) = vv;
        }
        __syncthreads();
        short8 a = *(short8*)(lds + AOFF + arow * 256 + ((kq * 64 + hi * 16) ^ asw));
        #pragma unroll
        for (int ct = 0; ct < 8; ++ct) {
            int bcol = ct * 16 + li;
            short8 bb = *(short8*)(lds + bcol * 64 + hi * 16);
            C1[ct] = __builtin_amdgcn_mfma_f32_16x16x32_bf16(a, bb, C1[ct], 0, 0, 0);
        }
    }
    __syncthreads();        // all MFMA reads of A done before H overwrite
    #pragma unroll
    for (int ct = 0; ct < 8; ++ct) {
        int col = ct * 16 + li;
        float bv = mb1[col];
        #pragma unroll
        for (int r = 0; r < 4; ++r) {
            int hrow = w * 16 + hi * 4 + r;
            float h = fmaxf(C1[ct][r] + bv, 0.0f);
            *(ushort*)(lds + AOFF + hrow * 256 + ((col * 2) ^ ((hrow & 7) << 4))) = f2bf(h);
        }
    }

    // ---- Phase E: MLP2 (same quarter staging) + residual + LN + out ----
    f32x4 C2[8];
    #pragma unroll
    for (int ct = 0; ct < 8; ++ct) C2[ct] = (f32x4){0.f, 0.f, 0.f, 0.f};
    #pragma unroll
    for (int kq = 0; kq < 4; ++kq) {
        __syncthreads();
        for (int cc = 0; cc < 2; ++cc) {
            int idx = cc * 256 + tid;
            int col = idx >> 2, ch = idx & 3;
            uint4 vv = *(const uint4*)(M2t + col * 128 + kq * 32 + ch * 8);
            *(uint4*)(lds + col * 64 + ch * 16) = vv;
        }
        __syncthreads();
        short8 a = *(short8*)(lds + AOFF + arow * 256 + ((kq * 64 + hi * 16) ^ asw));
        #pragma unroll
        for (int ct = 0; ct < 8; ++ct) {
            int bcol = ct * 16 + li;
            short8 bb = *(short8*)(lds + bcol * 64 + hi * 16);
            C2[ct] = __builtin_amdgcn_mfma_f32_16x16x32_bf16(a, bb, C2[ct], 0, 0, 0);
        }
    }

    float y[8][4];
    #pragma unroll
    for (int ct = 0; ct < 8; ++ct) {
        int col = ct * 16 + li;
        float bv = mb2[col];
        #pragma unroll
        for (int r = 0; r < 4; ++r) {
            int gr = baseNode + w * 16 + hi * 4 + r;
            int grc = gr < N ? gr : N - 1;
            y[ct][r] = C2[ct][r] + bv + bf2f(embh[(size_t)grc * 128 + col]);
        }
    }
    float rs[4] = {0, 0, 0, 0}, rq[4] = {0, 0, 0, 0};
    #pragma unroll
    for (int ct = 0; ct < 8; ++ct)
        #pragma unroll
        for (int r = 0; r < 4; ++r) { rs[r] += y[ct][r]; rq[r] += y[ct][r] * y[ct][r]; }
    #pragma unroll
    for (int m = 1; m < 16; m <<= 1) {
        #pragma unroll
        for (int r = 0; r < 4; ++r) {
            rs[r] += __shfl_xor(rs[r], m);
            rq[r] += __shfl_xor(rq[r], m);
        }
    }
    float mu[4], rstd[4];
    #pragma unroll
    for (int r = 0; r < 4; ++r) {
        mu[r] = rs[r] * (1.0f / HID);
        float var = rq[r] * (1.0f / HID) - mu[r] * mu[r];
        rstd[r] = rsqrtf(var + 1e-5f);
    }
    float cs[8];
    #pragma unroll
    for (int ct = 0; ct < 8; ++ct) {
        cs[ct] = 0.0f;
        int col = ct * 16 + li;
        float g = ln_g[col], bb2 = ln_b[col];
        #pragma unroll
        for (int r = 0; r < 4; ++r) {
            int gr = baseNode + w * 16 + hi * 4 + r;
            float o = (y[ct][r] - mu[r]) * rstd[r] * g + bb2;
            if (gr < N) {
                out[(size_t)gr * 128 + col] = o;
                cs[ct] += o;
            }
        }
    }

    #pragma unroll
    for (int m = 16; m < 64; m <<= 1) {
        #pragma unroll
        for (int ct = 0; ct < 8; ++ct) cs[ct] += __shfl_xor(cs[ct], m);
    }
    float* wsum = (float*)lds;              // weight region dead now
    __syncthreads();
    if (hi == 0) {
        #pragma unroll
        for (int ct = 0; ct < 8; ++ct) wsum[w * 128 + ct * 16 + li] = cs[ct];
    }
    __syncthreads();
    if (tid < 128) {
        float s = wsum[tid] + wsum[128 + tid] + wsum[256 + tid] + wsum[384 + tid];
        atomicAdd(&gsum[tid], s);
    }
}

// ---------------------------------------------------------------------------
__global__ void k_graph(const float* __restrict__ gsum, float* __restrict__ out,
                        int N)
{
    int j = threadIdx.x;
    out[(size_t)N * HID + j] = gsum[j] * (1.0f / (float)N);
}

// ---------------------------------------------------------------------------
extern "C" void kernel_launch(void* const* d_in, const int* in_sizes, int n_in,
                              void* d_out, int out_size, void* d_ws, size_t ws_size,
                              hipStream_t stream)
{
    const float* feat      = (const float*)d_in[0];
    const int*   role_ids  = (const int*)  d_in[1];
    const int*   b2b_src   = (const int*)  d_in[2];
    const int*   b2b_dst   = (const int*)  d_in[3];
    const float* b2b_w     = (const float*)d_in[4];
    const int*   p2b_block = (const int*)  d_in[5];
    const float* p2b_w     = (const float*)d_in[6];
    const float* role_emb  = (const float*)d_in[7];
    const float* idx_emb   = (const float*)d_in[8];
    const float* W1        = (const float*)d_in[9];
    const float* b1        = (const float*)d_in[10];
    const float* W2        = (const float*)d_in[11];
    const float* b2        = (const float*)d_in[12];
    const float* M1        = (const float*)d_in[13];
    const float* mb1       = (const float*)d_in[14];
    const float* M2        = (const float*)d_in[15];
    const float* mb2       = (const float*)d_in[16];
    const float* ln_g      = (const float*)d_in[17];
    const float* ln_b      = (const float*)d_in[18];

    const int N = in_sizes[1];
    const int E = in_sizes[2];
    const int P = in_sizes[5];

    float* out = (float*)d_out;

    const int nbins = (N + BINN - 1) >> 6;            // 1563
    const int chunkE = (E + NSEG - 1) / NSEG;
    const int chunkP = (P + NSEG - 1) / NSEG;

    // workspace layout (16B aligned throughout)
    char* ws = (char*)d_ws;
    size_t embhBytes = (size_t)N * HID * sizeof(ushort);                 // 25.6 MB
    size_t embf8Bytes= (size_t)N * HID;                                  // 12.8 MB
    size_t stagBytes = (size_t)nbins * NSEG * BINP_SCAP * sizeof(uint);  // 51.2 MB
    size_t vecBytes  = (size_t)N * sizeof(float);                        // 400 KB

    ushort* embh    = (ushort*)ws;  ws += embhBytes;
    uchar*  embf8   = (uchar*)ws;   ws += embf8Bytes;
    uint*   staged  = (uint*)ws;    ws += stagBytes;
    float*  pw      = (float*)ws;   ws += vecBytes;   // zeroed
    float*  gsum    = (float*)ws;   ws += 512;        // zeroed
    ushort* W1t     = (ushort*)ws;  ws += 8192  * sizeof(ushort);
    ushort* W2t     = (ushort*)ws;  ws += 16384 * sizeof(ushort);
    ushort* M1t     = (ushort*)ws;  ws += 16384 * sizeof(ushort);
    ushort* M2t     = (ushort*)ws;  ws += 16384 * sizeof(ushort);

    // zero pw | gsum (contiguous)
    hipMemsetAsync(pw, 0, vecBytes + 512, stream);

    const int nEmbed = (N + 63) / 64;                 // 1563 (> NSEG)

    k_prep<<<224, 256, 0, stream>>>(W1, W2, M1, M2, W1t, W2t, M1t, M2t);

    k_embed_binp<<<nEmbed + NSEG, 256, 0, stream>>>(
        feat, role_ids, role_emb, idx_emb, W1t, b1, W2t, b2, embh, embf8,
        b2b_src, b2b_dst, b2b_w, staged, p2b_block, p2b_w, pw,
        N, E, P, nbins, chunkE, chunkP);

    k_agg_mlp<<<nbins, 256, 0, stream>>>(
        staged, embh, embf8, pw, M1t, M2t, mb1, mb2, ln_g, ln_b,
        out, gsum, N, nbins);

    k_graph<<<1, HID, 0, stream>>>(gsum, out, N);
}

// Round 22
// 193.823 us; speedup vs baseline: 1.0291x; 1.0291x over previous
//
#include <hip/hip_runtime.h>

#define FEAT 14
#define ROLE_DIM 16
#define IDX_DIM 8
#define IN_DIM 38       // 14 + 16 + 8
#define HID 128
#define IDX_VOCAB 1024
#define BINN 128        // nodes per bin
#define NBINS_MAX 800   // static LDS sizing (782 actual)
#define NSEG 1024       // binning blocks (= segments per bin); lambda~2.5
#define BINP_CAPT 8     // LDS buffer entries per bin per binp block
#define BINP_SCAP 16    // staged capacity per (bin, seg) = one 64B line
#define SORT_CAP 4096   // per-bin total entries ~2560 avg
#define SENT 0xFFFFFFFFu  // segment terminator (impossible entry)

typedef __attribute__((ext_vector_type(8))) short short8;
typedef __attribute__((ext_vector_type(4))) float f32x4;
typedef __attribute__((ext_vector_type(2))) float f32x2;

// bf16 round-to-nearest-even pack
__device__ __forceinline__ ushort f2bf(float f) {
    uint u = __float_as_uint(f);
    return (ushort)((u + 0x7FFFu + ((u >> 16) & 1u)) >> 16);
}
__device__ __forceinline__ float bf2f(ushort h) {
    return __uint_as_float((uint)h << 16);
}
// fp8 e4m3 (OCP on gfx950) encode
__device__ __forceinline__ uchar f2fp8(float f) {
    return (uchar)(__builtin_amdgcn_cvt_pk_fp8_f32(f, f, 0, false) & 0xff);
}

// ---------------------------------------------------------------------------
// Prep: bf16 + transpose of the 4 weight matrices.
// ---------------------------------------------------------------------------
__global__ void k_prep(const float* __restrict__ W1, const float* __restrict__ W2,
                       const float* __restrict__ M1, const float* __restrict__ M2,
                       ushort* __restrict__ W1t, ushort* __restrict__ W2t,
                       ushort* __restrict__ M1t, ushort* __restrict__ M2t)
{
    int t = blockIdx.x * 256 + threadIdx.x;
    if (t < 8192) {                    // W1t: 128 x 64
        int c = t >> 6, k = t & 63;
        W1t[t] = (k < IN_DIM) ? f2bf(W1[k * HID + c]) : (ushort)0;
    } else if (t < 24576) {            // W2t: 128 x 128
        int u = t - 8192; int c = u >> 7, k = u & 127;
        W2t[u] = f2bf(W2[k * HID + c]);
    } else if (t < 40960) {            // M1t
        int u = t - 24576; int c = u >> 7, k = u & 127;
        M1t[u] = f2bf(M1[k * HID + c]);
    } else if (t < 57344) {            // M2t
        int u = t - 40960; int c = u >> 7, k = u & 127;
        M2t[u] = f2bf(M2[k * HID + c]);
    }
}

// ---------------------------------------------------------------------------
// Embed role: embh = bf16(relu(relu(x@W1+b1)@W2+b2)); embf8 = fp8 replica.
// ---------------------------------------------------------------------------
#define LDSA 32768

__device__ __forceinline__ void embed_body(
    char* lds, int id,
    const float* __restrict__ feat, const int* __restrict__ role_ids,
    const float* __restrict__ role_emb, const float* __restrict__ idx_emb,
    const ushort* __restrict__ W1t, const float* __restrict__ b1,
    const ushort* __restrict__ W2t, const float* __restrict__ b2,
    ushort* __restrict__ embh, uchar* __restrict__ embf8, int N)
{
    const int tid = threadIdx.x;
    const int w = tid >> 6, l = tid & 63;
    const int li = l & 15, hi = l >> 4;
    const int base = id * 64;

    // stage W1t (16KB) : [128 cols][64 k] -> 8 x 16B chunks per col
    for (int c = 0; c < 4; ++c) {
        int idx = c * 256 + tid;
        int col = idx >> 3, ch = idx & 7;
        uint4 v = *(const uint4*)(W1t + col * 64 + ch * 8);
        *(uint4*)(lds + col * 256 + ((ch * 16) ^ ((col & 7) << 4))) = v;
    }
    // build x-tile [64 rows][64 k] bf16 at LDSA
    {
        int row = tid >> 2, kq = (tid & 3) * 16;
        int gr = base + row; if (gr >= N) gr = N - 1;
        int rid = role_ids[gr];
        float xv[16];
        #pragma unroll
        for (int j = 0; j < 16; ++j) {
            int k = kq + j;
            float v = 0.0f;
            if (k < FEAT)                 v = feat[gr * FEAT + k];
            else if (k < FEAT + ROLE_DIM) v = role_emb[rid * ROLE_DIM + (k - FEAT)];
            else if (k < IN_DIM)          v = idx_emb[(gr & (IDX_VOCAB - 1)) * IDX_DIM + (k - FEAT - ROLE_DIM)];
            xv[j] = v;
        }
        uint p[8];
        #pragma unroll
        for (int j = 0; j < 8; ++j)
            p[j] = (uint)f2bf(xv[2 * j]) | ((uint)f2bf(xv[2 * j + 1]) << 16);
        char* db = lds + LDSA + row * 256;
        int sw = (row & 7) << 4;
        *(uint4*)(db + ((kq * 2) ^ sw))      = make_uint4(p[0], p[1], p[2], p[3]);
        *(uint4*)(db + ((kq * 2 + 16) ^ sw)) = make_uint4(p[4], p[5], p[6], p[7]);
    }
    __syncthreads();

    // phase 1: K=64
    f32x4 C[8];
    #pragma unroll
    for (int ct = 0; ct < 8; ++ct) C[ct] = (f32x4){0.f, 0.f, 0.f, 0.f};
    {
        const int arow = w * 16 + li;
        const int asw = (arow & 7) << 4;
        #pragma unroll
        for (int ks = 0; ks < 2; ++ks) {
            short8 a = *(short8*)(lds + LDSA + arow * 256 + ((ks * 64 + hi * 16) ^ asw));
            #pragma unroll
            for (int ct = 0; ct < 8; ++ct) {
                int bcol = ct * 16 + li;
                short8 b = *(short8*)(lds + bcol * 256 + ((ks * 64 + hi * 16) ^ ((bcol & 7) << 4)));
                C[ct] = __builtin_amdgcn_mfma_f32_16x16x32_bf16(a, b, C[ct], 0, 0, 0);
            }
        }
    }
    __syncthreads();

    // H = relu(C+b1) bf16 -> LDSA; stage W2t (32KB)
    #pragma unroll
    for (int ct = 0; ct < 8; ++ct) {
        int col = ct * 16 + li;
        float bv = b1[col];
        #pragma unroll
        for (int r = 0; r < 4; ++r) {
            int hrow = w * 16 + hi * 4 + r;
            float h = fmaxf(C[ct][r] + bv, 0.0f);
            *(ushort*)(lds + LDSA + hrow * 256 + ((col * 2) ^ ((hrow & 7) << 4))) = f2bf(h);
        }
    }
    for (int c = 0; c < 8; ++c) {
        int idx = c * 256 + tid;
        int col = idx >> 4, ch = idx & 15;
        uint4 v = *(const uint4*)(W2t + col * 128 + ch * 8);
        *(uint4*)(lds + col * 256 + ((ch * 16) ^ ((col & 7) << 4))) = v;
    }
    __syncthreads();

    // phase 2: K=128
    f32x4 C2[8];
    #pragma unroll
    for (int ct = 0; ct < 8; ++ct) C2[ct] = (f32x4){0.f, 0.f, 0.f, 0.f};
    {
        const int arow = w * 16 + li;
        const int asw = (arow & 7) << 4;
        #pragma unroll
        for (int ks = 0; ks < 4; ++ks) {
            short8 a = *(short8*)(lds + LDSA + arow * 256 + ((ks * 64 + hi * 16) ^ asw));
            #pragma unroll
            for (int ct = 0; ct < 8; ++ct) {
                int bcol = ct * 16 + li;
                short8 b = *(short8*)(lds + bcol * 256 + ((ks * 64 + hi * 16) ^ ((bcol & 7) << 4)));
                C2[ct] = __builtin_amdgcn_mfma_f32_16x16x32_bf16(a, b, C2[ct], 0, 0, 0);
            }
        }
    }

    // epilogue
    #pragma unroll
    for (int ct = 0; ct < 8; ++ct) {
        int col = ct * 16 + li;
        float bv = b2[col];
        #pragma unroll
        for (int r = 0; r < 4; ++r) {
            int gr = base + w * 16 + hi * 4 + r;
            if (gr < N) {
                float o = fmaxf(C2[ct][r] + bv, 0.0f);
                embh[(size_t)gr * 128 + col] = f2bf(o);
                embf8[(size_t)gr * 128 + col] = f2fp8(o);
            }
        }
    }
}

// ---------------------------------------------------------------------------
// Binp role: LDS-buffered private-segment binning + fused pin histogram.
// Self-describing segments (SENT terminator). entry (4B) =
// (node&127)<<25 | nbr<<8 | round(w*255).
// ---------------------------------------------------------------------------
__device__ __forceinline__ void binp_body(
    char* lds, int id,
    const int* __restrict__ src, const int* __restrict__ dst,
    const float* __restrict__ wgt, uint* __restrict__ staged,
    const int* __restrict__ pb, const float* __restrict__ pv,
    float* __restrict__ pw,
    int E, int P, int nbins, int chunkE, int chunkP)
{
    uint* buf   = (uint*)lds;                       // 800*8*4 = 25600
    int* curT   = (int*)(lds + 25600);              // 3200
    const int tid = threadIdx.x;
    for (int i = tid; i < nbins; i += 256) curT[i] = 0;
    __syncthreads();

    const int lo = id * chunkE;
    const int hiE = (lo + chunkE) < E ? (lo + chunkE) : E;
    for (int i = lo + tid; i < hiE; i += 256) {
        int s = src[i], d = dst[i];
        uint q = (uint)(wgt[i] * 255.0f + 0.5f);
        int bs = s >> 7;
        uint es = ((uint)(s & 127) << 25) | ((uint)d << 8) | q;
        int ps = atomicAdd(&curT[bs], 1);
        if (ps < BINP_CAPT) buf[bs * BINP_CAPT + ps] = es;
        else if (ps < BINP_SCAP)
            staged[((size_t)bs * NSEG + id) * BINP_SCAP + ps] = es;
        int bd = d >> 7;
        uint ed = ((uint)(d & 127) << 25) | ((uint)s << 8) | q;
        int pd = atomicAdd(&curT[bd], 1);
        if (pd < BINP_CAPT) buf[bd * BINP_CAPT + pd] = ed;
        else if (pd < BINP_SCAP)
            staged[((size_t)bd * NSEG + id) * BINP_SCAP + pd] = ed;
    }
    __syncthreads();
    for (int b = tid; b < nbins; b += 256) {
        int tot = curT[b];
        int k = tot < BINP_CAPT ? tot : BINP_CAPT;
        uint* dp = staged + ((size_t)b * NSEG + id) * BINP_SCAP;
        for (int i = 0; i < k; ++i) dp[i] = buf[b * BINP_CAPT + i];
        if (tot < BINP_SCAP) dp[tot] = SENT;   // terminator (same 64B line)
    }

    // fused pin-weight histogram (1M atomics over 100K addresses — fine)
    int loP = id * chunkP;
    int hiP = loP + chunkP; if (hiP > P) hiP = P;
    for (int i = loP + tid; i < hiP; i += 256)
        atomicAdd(&pw[pb[i]], pv[i]);
}

// ---------------------------------------------------------------------------
// Merged heterogeneous dispatch: interleaved embed / binp blocks.
// ---------------------------------------------------------------------------
__global__ __launch_bounds__(256) void k_embed_binp(
    const float* __restrict__ feat, const int* __restrict__ role_ids,
    const float* __restrict__ role_emb, const float* __restrict__ idx_emb,
    const ushort* __restrict__ W1t, const float* __restrict__ b1,
    const ushort* __restrict__ W2t, const float* __restrict__ b2,
    ushort* __restrict__ embh, uchar* __restrict__ embf8,
    const int* __restrict__ src, const int* __restrict__ dst,
    const float* __restrict__ wgt, uint* __restrict__ staged,
    const int* __restrict__ pb, const float* __restrict__ pv,
    float* __restrict__ pw,
    int N, int E, int P, int nbins, int chunkE, int chunkP)
{
    __shared__ char lds[49152];
    const int bid = blockIdx.x;
    int role, id;
    if (bid < 2 * NSEG) { role = bid & 1; id = bid >> 1; }
    else                { role = 0; id = NSEG + (bid - 2 * NSEG); }

    if (role == 0)
        embed_body(lds, id, feat, role_ids, role_emb, idx_emb,
                   W1t, b1, W2t, b2, embh, embf8, N);
    else
        binp_body(lds, id, src, dst, wgt, staged, pb, pv, pw,
                  E, P, nbins, chunkE, chunkP);
}

// ---------------------------------------------------------------------------
// FUSED k_agg_mlp v2: 50KB LDS -> 3 blocks/CU. Weights staged in 16KB
// K-halves into the sort-scratch region; accumulators carry across halves.
// LDS: [0,16K) sorted / weight-half; [16K,18K) aux (wsum later);
//      [18K,50K) A-tile 128 rows x 256B.
// ---------------------------------------------------------------------------
#define AOFF  18432
#define AUXO  16384

__global__ __launch_bounds__(256) void k_agg_mlp(
    const uint* __restrict__ staged,
    const ushort* __restrict__ embh, const uchar* __restrict__ embf8,
    const float* __restrict__ pw,
    const ushort* __restrict__ M1t, const ushort* __restrict__ M2t,
    const float* __restrict__ mb1, const float* __restrict__ mb2,
    const float* __restrict__ ln_g, const float* __restrict__ ln_b,
    float* __restrict__ out, float* __restrict__ gsum, int N, int nbins)
{
    __shared__ char lds[51200];
    uint* sorted  = (uint*)lds;                    // [0,16K)
    int*  hist    = (int*)(lds + AUXO);
    int*  startL  = (int*)(lds + AUXO + 512);
    int*  curL    = (int*)(lds + AUXO + 1024);
    int*  sc      = (int*)(lds + AUXO + 1536);

    const int tid = threadIdx.x;
    const int b = blockIdx.x;
    const int baseNode = b << 7;
    const int w = tid >> 6, l = tid & 63;
    const int li = l & 15, hi = l >> 4;

    if (tid < BINN) hist[tid] = 0;
    __syncthreads();

    // ---- Phase A: load 4 segments (4x uint4 each) into registers ----
    uint4 ent[4][4];
    int cSeg[4];
    #pragma unroll
    for (int ss = 0; ss < 4; ++ss) {
        int seg = ss * 256 + tid;
        const uint4* sp4 = (const uint4*)(staged + ((size_t)b * NSEG + seg) * BINP_SCAP);
        #pragma unroll
        for (int q = 0; q < 4; ++q) ent[ss][q] = sp4[q];
        int c = 16;
        #pragma unroll
        for (int q = 3; q >= 0; --q) {
            if (ent[ss][q].w == SENT) c = q * 4 + 3;
            if (ent[ss][q].z == SENT) c = q * 4 + 2;
            if (ent[ss][q].y == SENT) c = q * 4 + 1;
            if (ent[ss][q].x == SENT) c = q * 4 + 0;
        }
        cSeg[ss] = c;
    }
    // histogram from registers
    #pragma unroll
    for (int ss = 0; ss < 4; ++ss) {
        int c = cSeg[ss];
        #pragma unroll
        for (int q = 0; q < 4; ++q) {
            uint e0 = ent[ss][q].x, e1 = ent[ss][q].y;
            uint e2 = ent[ss][q].z, e3 = ent[ss][q].w;
            if (q * 4 + 0 < c) atomicAdd(&hist[e0 >> 25], 1);
            if (q * 4 + 1 < c) atomicAdd(&hist[e1 >> 25], 1);
            if (q * 4 + 2 < c) atomicAdd(&hist[e2 >> 25], 1);
            if (q * 4 + 3 < c) atomicAdd(&hist[e3 >> 25], 1);
        }
    }
    __syncthreads();

    int v = (tid < BINN) ? hist[tid] : 0;
    if (tid < BINN) sc[tid] = v;
    __syncthreads();
    for (int off = 1; off < BINN; off <<= 1) {
        int u = (tid < BINN && tid >= off) ? sc[tid - off] : 0;
        __syncthreads();
        if (tid < BINN) sc[tid] += u;
        __syncthreads();
    }
    if (tid < BINN) {
        startL[tid] = sc[tid] - v;
        curL[tid]   = sc[tid] - v;
    }
    __syncthreads();

    // placement from registers
    #pragma unroll
    for (int ss = 0; ss < 4; ++ss) {
        int c = cSeg[ss];
        #pragma unroll
        for (int q = 0; q < 4; ++q) {
            uint ee[4] = {ent[ss][q].x, ent[ss][q].y, ent[ss][q].z, ent[ss][q].w};
            #pragma unroll
            for (int j = 0; j < 4; ++j) {
                if (q * 4 + j < c) {
                    uint e = ee[j];
                    int pos = atomicAdd(&curL[e >> 25], 1);
                    if (pos < SORT_CAP) sorted[pos] = e;
                }
            }
        }
    }
    __syncthreads();

    // ---- Phase B: gather -> bf16 A-tile in LDS (4 rounds x 32 nodes) ----
    {
        const int g  = tid >> 3;
        const int cg = tid & 7;
        const int c0 = cg * 16;
        for (int h = 0; h < 4; ++h) {
            int nl = h * 32 + g;
            int node = baseNode + nl;
            uint p[8];
            if (node < N) {
                float acc[16];
                float pwn = pw[node];
                const uint4* r = (const uint4*)(embh + ((size_t)node << 7) + c0);
                uint4 u0 = r[0], u1 = r[1];
                uint uu[8] = {u0.x, u0.y, u0.z, u0.w, u1.x, u1.y, u1.z, u1.w};
                #pragma unroll
                for (int j = 0; j < 8; ++j) {
                    acc[2*j]   = __uint_as_float(uu[j] << 16) * pwn;
                    acc[2*j+1] = __uint_as_float(uu[j] & 0xffff0000u) * pwn;
                }
                const int st = startL[nl], deg = hist[nl];
                #pragma unroll 4
                for (int i = 0; i < deg; ++i) {
                    uint en = sorted[st + i];
                    int nb   = (int)((en >> 8) & 0x1FFFFu);
                    float wt = (float)(en & 255u) * (1.0f / 255.0f);
                    uint4 q = *(const uint4*)(embf8 + ((size_t)nb << 7) + c0);
                    uint qq[4] = {q.x, q.y, q.z, q.w};
                    #pragma unroll
                    for (int j = 0; j < 4; ++j) {
                        f32x2 lo = __builtin_amdgcn_cvt_pk_f32_fp8(qq[j], false);
                        f32x2 hi2 = __builtin_amdgcn_cvt_pk_f32_fp8(qq[j], true);
                        acc[4*j+0] = fmaf(lo.x,  wt, acc[4*j+0]);
                        acc[4*j+1] = fmaf(lo.y,  wt, acc[4*j+1]);
                        acc[4*j+2] = fmaf(hi2.x, wt, acc[4*j+2]);
                        acc[4*j+3] = fmaf(hi2.y, wt, acc[4*j+3]);
                    }
                }
                #pragma unroll
                for (int j = 0; j < 8; ++j)
                    p[j] = (uint)f2bf(acc[2*j]) | ((uint)f2bf(acc[2*j+1]) << 16);
            } else {
                #pragma unroll
                for (int j = 0; j < 8; ++j) p[j] = 0;
            }
            char* db = lds + AOFF + nl * 256;
            int sw = (nl & 7) << 4;
            *(uint4*)(db + ((c0 * 2) ^ sw))      = make_uint4(p[0], p[1], p[2], p[3]);
            *(uint4*)(db + ((c0 * 2 + 16) ^ sw)) = make_uint4(p[4], p[5], p[6], p[7]);
        }
    }

    // ---- Phase D: MLP1, weights staged in 16KB K-halves ----
    #pragma unroll
    for (int h2 = 0; h2 < 2; ++h2) {
        f32x4 C1[8];
        #pragma unroll
        for (int ct = 0; ct < 8; ++ct) C1[ct] = (f32x4){0.f, 0.f, 0.f, 0.f};
        const int arow = h2 * 64 + w * 16 + li;
        const int asw = (arow & 7) << 4;
        #pragma unroll
        for (int kh = 0; kh < 2; ++kh) {
            __syncthreads();   // prior reads of weight region done (or Phase B)
            for (int cc = 0; cc < 4; ++cc) {
                int idx = cc * 256 + tid;            // 0..1023 16B chunks
                int col = idx >> 3, ch = idx & 7;
                uint4 vv = *(const uint4*)(M1t + col * 128 + kh * 64 + ch * 8);
                *(uint4*)(lds + col * 128 + ((ch * 16) ^ ((col & 7) << 4))) = vv;
            }
            __syncthreads();
            #pragma unroll
            for (int ksh = 0; ksh < 2; ++ksh) {
                int ks = kh * 2 + ksh;
                short8 a = *(short8*)(lds + AOFF + arow * 256 + ((ks * 64 + hi * 16) ^ asw));
                #pragma unroll
                for (int ct = 0; ct < 8; ++ct) {
                    int bcol = ct * 16 + li;
                    short8 bb = *(short8*)(lds + bcol * 128 + ((ksh * 64 + hi * 16) ^ ((bcol & 7) << 4)));
                    C1[ct] = __builtin_amdgcn_mfma_f32_16x16x32_bf16(a, bb, C1[ct], 0, 0, 0);
                }
            }
        }
        // H = relu(C1+mb1) over A rows of this half (wave-private 16-row band)
        #pragma unroll
        for (int ct = 0; ct < 8; ++ct) {
            int col = ct * 16 + li;
            float bv = mb1[col];
            #pragma unroll
            for (int r = 0; r < 4; ++r) {
                int hrow = h2 * 64 + w * 16 + hi * 4 + r;
                float h = fmaxf(C1[ct][r] + bv, 0.0f);
                *(ushort*)(lds + AOFF + hrow * 256 + ((col * 2) ^ ((hrow & 7) << 4))) = f2bf(h);
            }
        }
    }

    // ---- Phase E: MLP2 (same half-staging) + residual + LN + out + gsum ----
    float cs[8];
    #pragma unroll
    for (int ct = 0; ct < 8; ++ct) cs[ct] = 0.0f;

    #pragma unroll
    for (int h2 = 0; h2 < 2; ++h2) {
        f32x4 C2[8];
        #pragma unroll
        for (int ct = 0; ct < 8; ++ct) C2[ct] = (f32x4){0.f, 0.f, 0.f, 0.f};
        const int arow = h2 * 64 + w * 16 + li;
        const int asw = (arow & 7) << 4;
        #pragma unroll
        for (int kh = 0; kh < 2; ++kh) {
            __syncthreads();
            for (int cc = 0; cc < 4; ++cc) {
                int idx = cc * 256 + tid;
                int col = idx >> 3, ch = idx & 7;
                uint4 vv = *(const uint4*)(M2t + col * 128 + kh * 64 + ch * 8);
                *(uint4*)(lds + col * 128 + ((ch * 16) ^ ((col & 7) << 4))) = vv;
            }
            __syncthreads();
            #pragma unroll
            for (int ksh = 0; ksh < 2; ++ksh) {
                int ks = kh * 2 + ksh;
                short8 a = *(short8*)(lds + AOFF + arow * 256 + ((ks * 64 + hi * 16) ^ asw));
                #pragma unroll
                for (int ct = 0; ct < 8; ++ct) {
                    int bcol = ct * 16 + li;
                    short8 bb = *(short8*)(lds + bcol * 128 + ((ksh * 64 + hi * 16) ^ ((bcol & 7) << 4)));
                    C2[ct] = __builtin_amdgcn_mfma_f32_16x16x32_bf16(a, bb, C2[ct], 0, 0, 0);
                }
            }
        }

        float y[8][4];
        #pragma unroll
        for (int ct = 0; ct < 8; ++ct) {
            int col = ct * 16 + li;
            float bv = mb2[col];
            #pragma unroll
            for (int r = 0; r < 4; ++r) {
                int gr = baseNode + h2 * 64 + w * 16 + hi * 4 + r;
                int grc = gr < N ? gr : N - 1;
                y[ct][r] = C2[ct][r] + bv + bf2f(embh[(size_t)grc * 128 + col]);
            }
        }
        float rs[4] = {0, 0, 0, 0}, rq[4] = {0, 0, 0, 0};
        #pragma unroll
        for (int ct = 0; ct < 8; ++ct)
            #pragma unroll
            for (int r = 0; r < 4; ++r) { rs[r] += y[ct][r]; rq[r] += y[ct][r] * y[ct][r]; }
        #pragma unroll
        for (int m = 1; m < 16; m <<= 1) {
            #pragma unroll
            for (int r = 0; r < 4; ++r) {
                rs[r] += __shfl_xor(rs[r], m);
                rq[r] += __shfl_xor(rq[r], m);
            }
        }
        float mu[4], rstd[4];
        #pragma unroll
        for (int r = 0; r < 4; ++r) {
            mu[r] = rs[r] * (1.0f / HID);
            float var = rq[r] * (1.0f / HID) - mu[r] * mu[r];
            rstd[r] = rsqrtf(var + 1e-5f);
        }
        #pragma unroll
        for (int ct = 0; ct < 8; ++ct) {
            int col = ct * 16 + li;
            float g = ln_g[col], bb2 = ln_b[col];
            #pragma unroll
            for (int r = 0; r < 4; ++r) {
                int gr = baseNode + h2 * 64 + w * 16 + hi * 4 + r;
                float o = (y[ct][r] - mu[r]) * rstd[r] * g + bb2;
                if (gr < N) {
                    out[(size_t)gr * 128 + col] = o;
                    cs[ct] += o;
                }
            }
        }
    }

    #pragma unroll
    for (int m = 16; m < 64; m <<= 1) {
        #pragma unroll
        for (int ct = 0; ct < 8; ++ct) cs[ct] += __shfl_xor(cs[ct], m);
    }
    float* wsum = (float*)(lds + AUXO);   // aux region dead after Phase B
    __syncthreads();
    if (hi == 0) {
        #pragma unroll
        for (int ct = 0; ct < 8; ++ct) wsum[w * 128 + ct * 16 + li] = cs[ct];
    }
    __syncthreads();
    if (tid < 128) {
        float s = wsum[tid] + wsum[128 + tid] + wsum[256 + tid] + wsum[384 + tid];
        atomicAdd(&gsum[tid], s);
    }
}

// ---------------------------------------------------------------------------
__global__ void k_graph(const float* __restrict__ gsum, float* __restrict__ out,
                        int N)
{
    int j = threadIdx.x;
    out[(size_t)N * HID + j] = gsum[j] * (1.0f / (float)N);
}

// ---------------------------------------------------------------------------
extern "C" void kernel_launch(void* const* d_in, const int* in_sizes, int n_in,
                              void* d_out, int out_size, void* d_ws, size_t ws_size,
                              hipStream_t stream)
{
    const float* feat      = (const float*)d_in[0];
    const int*   role_ids  = (const int*)  d_in[1];
    const int*   b2b_src   = (const int*)  d_in[2];
    const int*   b2b_dst   = (const int*)  d_in[3];
    const float* b2b_w     = (const float*)d_in[4];
    const int*   p2b_block = (const int*)  d_in[5];
    const float* p2b_w     = (const float*)d_in[6];
    const float* role_emb  = (const float*)d_in[7];
    const float* idx_emb   = (const float*)d_in[8];
    const float* W1        = (const float*)d_in[9];
    const float* b1        = (const float*)d_in[10];
    const float* W2        = (const float*)d_in[11];
    const float* b2        = (const float*)d_in[12];
    const float* M1        = (const float*)d_in[13];
    const float* mb1       = (const float*)d_in[14];
    const float* M2        = (const float*)d_in[15];
    const float* mb2       = (const float*)d_in[16];
    const float* ln_g      = (const float*)d_in[17];
    const float* ln_b      = (const float*)d_in[18];

    const int N = in_sizes[1];
    const int E = in_sizes[2];
    const int P = in_sizes[5];

    float* out = (float*)d_out;

    const int nbins = (N + BINN - 1) >> 7;            // 782
    const int chunkE = (E + NSEG - 1) / NSEG;
    const int chunkP = (P + NSEG - 1) / NSEG;

    // workspace layout (16B aligned throughout)
    char* ws = (char*)d_ws;
    size_t embhBytes = (size_t)N * HID * sizeof(ushort);                 // 25.6 MB
    size_t embf8Bytes= (size_t)N * HID;                                  // 12.8 MB
    size_t stagBytes = (size_t)nbins * NSEG * BINP_SCAP * sizeof(uint);  // 51.2 MB
    size_t vecBytes  = (size_t)N * sizeof(float);                        // 400 KB

    ushort* embh    = (ushort*)ws;  ws += embhBytes;
    uchar*  embf8   = (uchar*)ws;   ws += embf8Bytes;
    uint*   staged  = (uint*)ws;    ws += stagBytes;
    float*  pw      = (float*)ws;   ws += vecBytes;   // zeroed
    float*  gsum    = (float*)ws;   ws += 512;        // zeroed
    ushort* W1t     = (ushort*)ws;  ws += 8192  * sizeof(ushort);
    ushort* W2t     = (ushort*)ws;  ws += 16384 * sizeof(ushort);
    ushort* M1t     = (ushort*)ws;  ws += 16384 * sizeof(ushort);
    ushort* M2t     = (ushort*)ws;  ws += 16384 * sizeof(ushort);

    // zero pw | gsum (contiguous)
    hipMemsetAsync(pw, 0, vecBytes + 512, stream);

    const int nEmbed = (N + 63) / 64;                 // 1563 (> NSEG)

    k_prep<<<224, 256, 0, stream>>>(W1, W2, M1, M2, W1t, W2t, M1t, M2t);

    k_embed_binp<<<nEmbed + NSEG, 256, 0, stream>>>(
        feat, role_ids, role_emb, idx_emb, W1t, b1, W2t, b2, embh, embf8,
        b2b_src, b2b_dst, b2b_w, staged, p2b_block, p2b_w, pw,
        N, E, P, nbins, chunkE, chunkP);

    k_agg_mlp<<<nbins, 256, 0, stream>>>(
        staged, embh, embf8, pw, M1t, M2t, mb1, mb2, ln_g, ln_b,
        out, gsum, N, nbins);

    k_graph<<<1, HID, 0, stream>>>(gsum, out, N);
}